// Round 1
// baseline (16936.728 us; speedup 1.0000x reference)
//
#include <hip/hip_runtime.h>
#include <math.h>

#define NSTEPS 200
#define DIMD   128
#define BR     64          // batch rows per block
#define NT     256         // threads per block
#define LSTR   132         // LDS row stride (floats): 16B-aligned rows, benign 2-way bank aliasing

__device__ __forceinline__ float gelu_f(float x) {
    // exact GELU: 0.5*x*(1+erf(x/sqrt(2)))
    return 0.5f * x * (1.0f + erff(x * 0.70710678118654752440f));
}

// acc[4][NQ*4] += src[r0..r0+3][0..127] @ W[0..127][cw0..cw0+NQ*4-1]
template<int WCOLS, int NQ>
__device__ __forceinline__ void gemm_acc(const float (*src)[LSTR], const float* __restrict__ W,
                                         int r0, int cw0, float acc[4][NQ * 4]) {
    for (int k = 0; k < DIMD; k += 4) {
        float4 zq[4];
        #pragma unroll
        for (int i = 0; i < 4; i++)
            zq[i] = *reinterpret_cast<const float4*>(&src[r0 + i][k]);
        #pragma unroll
        for (int kk = 0; kk < 4; kk++) {
            float4 w[NQ];
            #pragma unroll
            for (int q = 0; q < NQ; q++)
                w[q] = *reinterpret_cast<const float4*>(W + (size_t)(k + kk) * WCOLS + cw0 + q * 4);
            #pragma unroll
            for (int i = 0; i < 4; i++) {
                const float zv = (kk == 0) ? zq[i].x : (kk == 1) ? zq[i].y : (kk == 2) ? zq[i].z : zq[i].w;
                #pragma unroll
                for (int q = 0; q < NQ; q++) {
                    acc[i][q*4+0] = fmaf(zv, w[q].x, acc[i][q*4+0]);
                    acc[i][q*4+1] = fmaf(zv, w[q].y, acc[i][q*4+1]);
                    acc[i][q*4+2] = fmaf(zv, w[q].z, acc[i][q*4+2]);
                    acc[i][q*4+3] = fmaf(zv, w[q].w, acc[i][q*4+3]);
                }
            }
        }
    }
}

__global__ __launch_bounds__(NT) void sde_fused(
    const float* __restrict__ y,
    const float* __restrict__ noise,
    const float* __restrict__ enc_w, const float* __restrict__ enc_b,
    const float* __restrict__ mu_w1, const float* __restrict__ mu_b1,
    const float* __restrict__ mu_w2, const float* __restrict__ mu_b2,
    const float* __restrict__ sig_w, const float* __restrict__ sig_b,
    const float* __restrict__ dec_w, const float* __restrict__ dec_b,
    float* __restrict__ out, int Btot)
{
    __shared__ float zt[BR][LSTR];   // latent state tile
    __shared__ float ht[BR][LSTR];   // hidden / scratch tile
    __shared__ float ns[BR][2];      // per-step noise tile

    const int tid = threadIdx.x;
    const int tc  = tid & 15;        // 16 col-groups
    const int tr  = tid >> 4;        // 16 row-groups
    const int c0  = tc * 8;          // 8 output cols per thread
    const int r0  = tr * 4;          // 4 rows per thread
    const long brow = (long)blockIdx.x * BR;

    // ---- stage y tile into ht (coalesced float4) ----
    for (int i = tid; i < BR * (DIMD / 4); i += NT) {
        const int r  = i >> 5;            // DIMD/4 == 32 quads per row
        const int cq = (i & 31) << 2;
        const float4 v = *reinterpret_cast<const float4*>(y + (brow + r) * DIMD + cq);
        ht[r][cq] = v.x; ht[r][cq+1] = v.y; ht[r][cq+2] = v.z; ht[r][cq+3] = v.w;
    }
    __syncthreads();

    // ---- encoder: z0 = gelu(y @ enc_w + enc_b) ----
    {
        float acc[4][8];
        #pragma unroll
        for (int j = 0; j < 8; j++) {
            const float b = enc_b[c0 + j];
            #pragma unroll
            for (int i = 0; i < 4; i++) acc[i][j] = b;
        }
        gemm_acc<DIMD, 2>(ht, enc_w, r0, c0, acc);
        #pragma unroll
        for (int i = 0; i < 4; i++)
            #pragma unroll
            for (int j = 0; j < 8; j++)
                zt[r0 + i][c0 + j] = gelu_f(acc[i][j]);
    }
    __syncthreads();

    const float dt   = 1.0f / NSTEPS;
    const float sqdt = 0.070710678118654752440f;  // sqrt(1/200)

    for (int t = 0; t < NSTEPS; t++) {
        // stage this step's noise (consumed after the mid barrier)
        if (tid < BR * 2) {
            const int r = tid >> 1, k = tid & 1;
            ns[r][k] = noise[((size_t)t * (size_t)Btot + (size_t)(brow + r)) * 2 + k];
        }

        // ---- GEMM1: h = gelu(z @ mu_w1 + mu_b1) -> ht ----
        {
            float acc[4][8];
            #pragma unroll
            for (int j = 0; j < 8; j++) {
                const float b = mu_b1[c0 + j];
                #pragma unroll
                for (int i = 0; i < 4; i++) acc[i][j] = b;
            }
            gemm_acc<DIMD, 2>(zt, mu_w1, r0, c0, acc);
            #pragma unroll
            for (int i = 0; i < 4; i++)
                #pragma unroll
                for (int j = 0; j < 8; j++)
                    ht[r0 + i][c0 + j] = gelu_f(acc[i][j]);
        }
        __syncthreads();

        // ---- GEMM2: drift = h @ mu_w2 + mu_b2 (registers) ----
        float da[4][8];
        #pragma unroll
        for (int j = 0; j < 8; j++) {
            const float b = mu_b2[c0 + j];
            #pragma unroll
            for (int i = 0; i < 4; i++) da[i][j] = b;
        }
        gemm_acc<DIMD, 2>(ht, mu_w2, r0, c0, da);

        // ---- GEMM3: g = z @ sig_w + sig_b, interleaved pairs (registers) ----
        float ga[4][16];
        #pragma unroll
        for (int m = 0; m < 16; m++) {
            const float b = sig_b[tc * 16 + m];
            #pragma unroll
            for (int i = 0; i < 4; i++) ga[i][m] = b;
        }
        gemm_acc<2 * DIMD, 4>(zt, sig_w, r0, tc * 16, ga);

        __syncthreads();  // all reads of zt/ns complete before update

        // ---- Euler-Maruyama update ----
        #pragma unroll
        for (int i = 0; i < 4; i++) {
            const float dw0 = ns[r0 + i][0] * sqdt;
            const float dw1 = ns[r0 + i][1] * sqdt;
            #pragma unroll
            for (int j = 0; j < 8; j++) {
                zt[r0 + i][c0 + j] += da[i][j] * dt + ga[i][2*j] * dw0 + ga[i][2*j + 1] * dw1;
            }
        }
        __syncthreads();
    }

    // ---- decoder: out = z @ dec_w + dec_b ----
    {
        float acc[4][8];
        #pragma unroll
        for (int j = 0; j < 8; j++) {
            const float b = dec_b[c0 + j];
            #pragma unroll
            for (int i = 0; i < 4; i++) acc[i][j] = b;
        }
        gemm_acc<DIMD, 2>(zt, dec_w, r0, c0, acc);
        #pragma unroll
        for (int i = 0; i < 4; i++) {
            float4 v0 = make_float4(acc[i][0], acc[i][1], acc[i][2], acc[i][3]);
            float4 v1 = make_float4(acc[i][4], acc[i][5], acc[i][6], acc[i][7]);
            float* p = out + (size_t)(brow + r0 + i) * DIMD + c0;
            *reinterpret_cast<float4*>(p)     = v0;
            *reinterpret_cast<float4*>(p + 4) = v1;
        }
    }
}

extern "C" void kernel_launch(void* const* d_in, const int* in_sizes, int n_in,
                              void* d_out, int out_size, void* d_ws, size_t ws_size,
                              hipStream_t stream) {
    const float* y     = (const float*)d_in[0];
    const float* noise = (const float*)d_in[1];
    const float* enc_w = (const float*)d_in[2];
    const float* enc_b = (const float*)d_in[3];
    const float* mu_w1 = (const float*)d_in[4];
    const float* mu_b1 = (const float*)d_in[5];
    const float* mu_w2 = (const float*)d_in[6];
    const float* mu_b2 = (const float*)d_in[7];
    const float* sig_w = (const float*)d_in[8];
    const float* sig_b = (const float*)d_in[9];
    const float* dec_w = (const float*)d_in[10];
    const float* dec_b = (const float*)d_in[11];
    float* out = (float*)d_out;

    const int Btot = in_sizes[0] / DIMD;   // 32768
    const int grid = Btot / BR;            // 512 blocks

    sde_fused<<<grid, NT, 0, stream>>>(y, noise, enc_w, enc_b, mu_w1, mu_b1,
                                       mu_w2, mu_b2, sig_w, sig_b, dec_w, dec_b,
                                       out, Btot);
}

// Round 5
// 8500.538 us; speedup vs baseline: 1.9924x; 1.9924x over previous
//
#include <hip/hip_runtime.h>
#include <math.h>

#define NSTEPS 200
#define NT     256
#define BR     64
#define SQDT_F 0.07071067811865475f
#define DT_F   0.005f
#define LOSCL  4096.0f            // 2^12
#define LOINV  2.44140625e-4f     // 2^-12

typedef float  f32x4 __attribute__((ext_vector_type(4)));
typedef short  s16x8 __attribute__((ext_vector_type(8)));
typedef unsigned short u16;
typedef unsigned short us4 __attribute__((ext_vector_type(4)));

// prepacked weight offsets in u16 units (each 128x128 matrix = 32768 u16 as hi/lo frags)
#define ENC_OFF 0
#define W1_OFF  32768
#define W2_OFF  65536
#define WG0_OFF 98304
#define WG1_OFF 131072
#define DEC_OFF 163840
#define WPK_TOT 196608

// ---- fp16 scaled two-term split: x ~= hi + lo*2^-12, |err| <= ~2^-23 |x| ----
// lo is stored PRE-SCALED by 2^12 so it stays in the fp16 normal range
// (raw lo of small weights would be denormal -> MFMA flush risk).
__device__ __forceinline__ u16 f2h(float v) {
    _Float16 h = (_Float16)v;                       // v_cvt_f16_f32, RNE
    return __builtin_bit_cast(u16, h);
}
__device__ __forceinline__ float h2f(u16 u) {
    return (float)__builtin_bit_cast(_Float16, u);
}
__device__ __forceinline__ u16 split_hi(float v) { return f2h(v); }
__device__ __forceinline__ u16 split_lo(float v, u16 hi) {
    return f2h((v - h2f(hi)) * LOSCL);              // v-hi exact in fp32; *2^12 exact
}
__device__ __forceinline__ float gelu_exact(float x) {
    // exact GELU to match reference erf; approx GELU re-rolls the chaotic
    // trajectory at the ~1e-3 level (rounds 2/3 post-mortem).
    return 0.5f * x * (1.0f + erff(x * 0.70710678118654752f));
}

__device__ __forceinline__ void mfma16(f32x4& d, s16x8 a, s16x8 b) {
    asm("v_mfma_f32_16x16x32_f16 %0, %1, %2, %0" : "+v"(d) : "v"(a), "v"(b));
}
__device__ __forceinline__ s16x8 ldf(const u16* p) {
    return *reinterpret_cast<const s16x8*>(p);
}

// ---------------- weight prepack: fp32 -> fp16 hi / scaled-lo fragments ----------------
// frag layout: base + ((nt*4 + kc)*2 + term)*512 + lane*8 + i   (u16 units)
// element: B[k = kc*32 + (lane>>4)*8 + i][n = nt*16 + (lane&15)]
// sigma is column-deinterleaved: WG0 = sig_w[:,0::2], WG1 = sig_w[:,1::2]
__global__ void prepack(const float* __restrict__ enc_w, const float* __restrict__ mu_w1,
                        const float* __restrict__ mu_w2, const float* __restrict__ sig_w,
                        const float* __restrict__ dec_w, u16* __restrict__ wpk)
{
    int u = blockIdx.x * 256 + threadIdx.x;
    if (u >= WPK_TOT) return;
    int mat  = u >> 15;
    int r    = u & 32767;
    int i    = r & 7;
    int lane = (r >> 3) & 63;
    int term = (r >> 9) & 1;
    int kc   = (r >> 10) & 3;
    int nt   = (r >> 12) & 7;
    int k = kc * 32 + (lane >> 4) * 8 + i;
    int n = nt * 16 + (lane & 15);
    float v;
    switch (mat) {
        case 0:  v = enc_w[k * 128 + n];         break;
        case 1:  v = mu_w1[k * 128 + n];         break;
        case 2:  v = mu_w2[k * 128 + n];         break;
        case 3:  v = sig_w[k * 256 + 2 * n];     break;
        case 4:  v = sig_w[k * 256 + 2 * n + 1]; break;
        default: v = dec_w[k * 128 + n];         break;
    }
    u16 hi = split_hi(v);
    wpk[u] = term ? split_lo(v, hi) : hi;
}

// ---------------- GEMM helper ----------------
// A tiles (64x128, fp16 hi/lo) in LDS, XOR-swizzled on 16B chunks:
//   u16 idx(row,k) = row*128 + (((k>>3) ^ (row&7))<<3) + (k&7)
// wave `wid` computes output cols [32*wid, 32*wid+32): nt = 2*wid + j
// Result = a0 + a1 * 2^-12  (a0: hi*hi chain; a1: cross-term chain)
__device__ __forceinline__ void gemm_hilo(const u16* __restrict__ abh, const u16* __restrict__ abl,
                                          const u16* __restrict__ wf,
                                          int wid, int lane, int ln, int lg,
                                          f32x4 a0[4][2], f32x4 a1[4][2])
{
    #pragma unroll
    for (int kc = 0; kc < 4; kc++) {
        s16x8 ah[4], al[4];
        #pragma unroll
        for (int mt = 0; mt < 4; mt++) {
            int row = mt * 16 + ln;
            int idx = row * 128 + ((((kc << 2) | lg) ^ (row & 7)) << 3);
            ah[mt] = ldf(abh + idx);
            al[mt] = ldf(abl + idx);
        }
        #pragma unroll
        for (int j = 0; j < 2; j++) {
            int nt = wid * 2 + j;
            const u16* wp = wf + (((nt << 2) | kc) << 10) + (lane << 3);
            s16x8 bh = ldf(wp);
            s16x8 bl = ldf(wp + 512);
            #pragma unroll
            for (int mt = 0; mt < 4; mt++) {
                mfma16(a0[mt][j], ah[mt], bh);   // hi*hi
                mfma16(a1[mt][j], al[mt], bh);   // lo*hi   (scaled by 2^12)
                mfma16(a1[mt][j], ah[mt], bl);   // hi*lo   (scaled by 2^12)
                // lo*lo term ~2^-24 relative: below fp32 rounding, dropped
            }
        }
    }
}

// ---------------- main fused SDE kernel ----------------
__global__ __launch_bounds__(NT, 2) void sde_mfma(
    const float* __restrict__ y, const float* __restrict__ noise,
    const float* __restrict__ enc_b, const float* __restrict__ mu_b1,
    const float* __restrict__ mu_b2, const float* __restrict__ sig_b,
    const float* __restrict__ dec_b, const u16* __restrict__ wpk,
    float* __restrict__ out, int Btot)
{
    __shared__ __align__(16) u16 zbh[8192];
    __shared__ __align__(16) u16 zbl[8192];
    __shared__ __align__(16) u16 hbh[8192];
    __shared__ __align__(16) u16 hbl[8192];
    __shared__ float nsb[2][128];

    const int tid  = threadIdx.x;
    const int lane = tid & 63, wid = tid >> 6;
    const int ln   = lane & 15, lg = lane >> 4;
    const size_t brow = (size_t)blockIdx.x * BR;

    const int n0 = wid * 32 + ln, n1 = n0 + 16;
    const float be0 = enc_b[n0],  be1 = enc_b[n1];
    const float b10 = mu_b1[n0],  b11 = mu_b1[n1];
    const float b20 = mu_b2[n0],  b21 = mu_b2[n1];
    const float bg00 = sig_b[2 * n0],     bg01 = sig_b[2 * n1];
    const float bg10 = sig_b[2 * n0 + 1], bg11 = sig_b[2 * n1 + 1];
    const float bd0 = dec_b[n0],  bd1 = dec_b[n1];

    float zr[4][2][4];   // z state: elem (m = 16*mt + 4*lg + r, n = 32*wid + 16*j + ln)

    // ---- stage y into zb (fp16 hi/lo, swizzled) ----
    #pragma unroll
    for (int c = 0; c < 8; c++) {
        int q = c * NT + tid;                 // 0..2047
        int row = q >> 5, k4 = (q & 31) << 2;
        const float4 v = *reinterpret_cast<const float4*>(y + (brow + row) * 128 + k4);
        int idx = row * 128 + ((((k4 >> 3) ^ (row & 7))) << 3) + (k4 & 7);
        float vv[4] = {v.x, v.y, v.z, v.w};
        us4 hv, lv;
        #pragma unroll
        for (int e = 0; e < 4; e++) {
            u16 h = split_hi(vv[e]);
            u16 l = split_lo(vv[e], h);
            hv[e] = h; lv[e] = l;
        }
        *reinterpret_cast<us4*>(zbh + idx) = hv;
        *reinterpret_cast<us4*>(zbl + idx) = lv;
    }
    __syncthreads();

    // ---- encoder: z0 = gelu_exact(y @ enc_w + enc_b) ----
    {
        f32x4 a0[4][2], a1[4][2];
        #pragma unroll
        for (int mt = 0; mt < 4; mt++) {
            a0[mt][0] = f32x4{be0, be0, be0, be0}; a0[mt][1] = f32x4{be1, be1, be1, be1};
            a1[mt][0] = f32x4{0, 0, 0, 0};        a1[mt][1] = f32x4{0, 0, 0, 0};
        }
        gemm_hilo(zbh, zbl, wpk + ENC_OFF, wid, lane, ln, lg, a0, a1);
        #pragma unroll
        for (int mt = 0; mt < 4; mt++)
            #pragma unroll
            for (int j = 0; j < 2; j++)
                #pragma unroll
                for (int r = 0; r < 4; r++)
                    zr[mt][j][r] = gelu_exact(fmaf(a1[mt][j][r], LOINV, a0[mt][j][r]));
    }
    __syncthreads();   // all reads of y-tile done

    // write z0 into zb; stage noise for t=0
    #pragma unroll
    for (int mt = 0; mt < 4; mt++)
        #pragma unroll
        for (int j = 0; j < 2; j++)
            #pragma unroll
            for (int r = 0; r < 4; r++) {
                int m = 16 * mt + 4 * lg + r, n = j ? n1 : n0;
                int idx = m * 128 + ((((n >> 3) ^ (m & 7))) << 3) + (n & 7);
                u16 h = split_hi(zr[mt][j][r]);
                zbh[idx] = h;
                zbl[idx] = split_lo(zr[mt][j][r], h);
            }
    if (tid < 128) nsb[0][tid] = noise[brow * 2 + tid];
    __syncthreads();

    // ---- 200 Euler-Maruyama steps, 2 barriers each ----
    for (int t = 0; t < NSTEPS; t++) {
        {   // prefetch next step's noise into the other buffer
            int tn = (t + 1 < NSTEPS) ? (t + 1) : t;
            if (tid < 128) nsb[(t + 1) & 1][tid] = noise[((size_t)tn * Btot + brow) * 2 + tid];
        }
        // G1: h = gelu(z @ W1 + b1) -> hb
        {
            f32x4 a0[4][2], a1[4][2];
            #pragma unroll
            for (int mt = 0; mt < 4; mt++) {
                a0[mt][0] = f32x4{b10, b10, b10, b10}; a0[mt][1] = f32x4{b11, b11, b11, b11};
                a1[mt][0] = f32x4{0, 0, 0, 0};        a1[mt][1] = f32x4{0, 0, 0, 0};
            }
            gemm_hilo(zbh, zbl, wpk + W1_OFF, wid, lane, ln, lg, a0, a1);
            #pragma unroll
            for (int mt = 0; mt < 4; mt++)
                #pragma unroll
                for (int j = 0; j < 2; j++)
                    #pragma unroll
                    for (int r = 0; r < 4; r++) {
                        float hv = gelu_exact(fmaf(a1[mt][j][r], LOINV, a0[mt][j][r]));
                        int m = 16 * mt + 4 * lg + r, n = j ? n1 : n0;
                        int idx = m * 128 + ((((n >> 3) ^ (m & 7))) << 3) + (n & 7);
                        u16 h = split_hi(hv);
                        hbh[idx] = h;
                        hbl[idx] = split_lo(hv, h);
                    }
        }
        const float* np = nsb[t & 1];
        // G3a: g0 = z @ Wg0 + bg0; z += g0*dw0  (applied immediately, frees regs)
        {
            f32x4 a0[4][2], a1[4][2];
            #pragma unroll
            for (int mt = 0; mt < 4; mt++) {
                a0[mt][0] = f32x4{bg00, bg00, bg00, bg00}; a0[mt][1] = f32x4{bg01, bg01, bg01, bg01};
                a1[mt][0] = f32x4{0, 0, 0, 0};             a1[mt][1] = f32x4{0, 0, 0, 0};
            }
            gemm_hilo(zbh, zbl, wpk + WG0_OFF, wid, lane, ln, lg, a0, a1);
            #pragma unroll
            for (int mt = 0; mt < 4; mt++)
                #pragma unroll
                for (int r = 0; r < 4; r++) {
                    int m = 16 * mt + 4 * lg + r;
                    float dw0 = np[2 * m] * SQDT_F;
                    #pragma unroll
                    for (int j = 0; j < 2; j++)
                        zr[mt][j][r] = fmaf(fmaf(a1[mt][j][r], LOINV, a0[mt][j][r]), dw0, zr[mt][j][r]);
                }
        }
        // G3b: g1 = z @ Wg1 + bg1; z += g1*dw1
        {
            f32x4 a0[4][2], a1[4][2];
            #pragma unroll
            for (int mt = 0; mt < 4; mt++) {
                a0[mt][0] = f32x4{bg10, bg10, bg10, bg10}; a0[mt][1] = f32x4{bg11, bg11, bg11, bg11};
                a1[mt][0] = f32x4{0, 0, 0, 0};             a1[mt][1] = f32x4{0, 0, 0, 0};
            }
            gemm_hilo(zbh, zbl, wpk + WG1_OFF, wid, lane, ln, lg, a0, a1);
            #pragma unroll
            for (int mt = 0; mt < 4; mt++)
                #pragma unroll
                for (int r = 0; r < 4; r++) {
                    int m = 16 * mt + 4 * lg + r;
                    float dw1 = np[2 * m + 1] * SQDT_F;
                    #pragma unroll
                    for (int j = 0; j < 2; j++)
                        zr[mt][j][r] = fmaf(fmaf(a1[mt][j][r], LOINV, a0[mt][j][r]), dw1, zr[mt][j][r]);
                }
        }
        __syncthreads();   // bar1: hb visible; all zb reads complete

        // G2: drift = h @ W2 + b2; z += drift*dt; rewrite zb
        {
            f32x4 a0[4][2], a1[4][2];
            #pragma unroll
            for (int mt = 0; mt < 4; mt++) {
                a0[mt][0] = f32x4{b20, b20, b20, b20}; a0[mt][1] = f32x4{b21, b21, b21, b21};
                a1[mt][0] = f32x4{0, 0, 0, 0};        a1[mt][1] = f32x4{0, 0, 0, 0};
            }
            gemm_hilo(hbh, hbl, wpk + W2_OFF, wid, lane, ln, lg, a0, a1);
            #pragma unroll
            for (int mt = 0; mt < 4; mt++)
                #pragma unroll
                for (int j = 0; j < 2; j++)
                    #pragma unroll
                    for (int r = 0; r < 4; r++) {
                        float v = fmaf(fmaf(a1[mt][j][r], LOINV, a0[mt][j][r]), DT_F, zr[mt][j][r]);
                        zr[mt][j][r] = v;
                        int m = 16 * mt + 4 * lg + r, n = j ? n1 : n0;
                        int idx = m * 128 + ((((n >> 3) ^ (m & 7))) << 3) + (n & 7);
                        u16 h = split_hi(v);
                        zbh[idx] = h;
                        zbl[idx] = split_lo(v, h);
                    }
        }
        __syncthreads();   // bar2: new zb visible
    }

    // ---- decoder: out = z @ dec_w + dec_b ----
    {
        f32x4 a0[4][2], a1[4][2];
        #pragma unroll
        for (int mt = 0; mt < 4; mt++) {
            a0[mt][0] = f32x4{bd0, bd0, bd0, bd0}; a0[mt][1] = f32x4{bd1, bd1, bd1, bd1};
            a1[mt][0] = f32x4{0, 0, 0, 0};        a1[mt][1] = f32x4{0, 0, 0, 0};
        }
        gemm_hilo(zbh, zbl, wpk + DEC_OFF, wid, lane, ln, lg, a0, a1);
        #pragma unroll
        for (int mt = 0; mt < 4; mt++)
            #pragma unroll
            for (int j = 0; j < 2; j++)
                #pragma unroll
                for (int r = 0; r < 4; r++) {
                    int m = 16 * mt + 4 * lg + r, n = j ? n1 : n0;
                    out[(brow + m) * 128 + n] = fmaf(a1[mt][j][r], LOINV, a0[mt][j][r]);
                }
    }
}

extern "C" void kernel_launch(void* const* d_in, const int* in_sizes, int n_in,
                              void* d_out, int out_size, void* d_ws, size_t ws_size,
                              hipStream_t stream) {
    const float* y     = (const float*)d_in[0];
    const float* noise = (const float*)d_in[1];
    const float* enc_w = (const float*)d_in[2];
    const float* enc_b = (const float*)d_in[3];
    const float* mu_w1 = (const float*)d_in[4];
    const float* mu_b1 = (const float*)d_in[5];
    const float* mu_w2 = (const float*)d_in[6];
    const float* mu_b2 = (const float*)d_in[7];
    const float* sig_w = (const float*)d_in[8];
    const float* sig_b = (const float*)d_in[9];
    const float* dec_w = (const float*)d_in[10];
    const float* dec_b = (const float*)d_in[11];
    float* out = (float*)d_out;
    u16* wpk = (u16*)d_ws;

    const int Btot = in_sizes[0] / 128;     // 32768
    prepack<<<(WPK_TOT + 255) / 256, 256, 0, stream>>>(enc_w, mu_w1, mu_w2, sig_w, dec_w, wpk);
    sde_mfma<<<Btot / BR, NT, 0, stream>>>(y, noise, enc_b, mu_b1, mu_b2, sig_b, dec_b,
                                           wpk, out, Btot);
}

// Round 8
// 5180.975 us; speedup vs baseline: 3.2690x; 1.6407x over previous
//
#include <hip/hip_runtime.h>
#include <math.h>

#define NSTEPS 200
#define NT     512          // 8 waves; each wave owns 16 output cols
#define BR     64
#define SQDT_F 0.07071067811865475f
#define DT_F   0.005f
#define LOSCL  4096.0f            // 2^12
#define LOINV  2.44140625e-4f     // 2^-12

typedef float  f32x4 __attribute__((ext_vector_type(4)));
typedef short  s16x8 __attribute__((ext_vector_type(8)));
typedef _Float16 h16x8 __attribute__((ext_vector_type(8)));
typedef unsigned short u16;
typedef unsigned short us4 __attribute__((ext_vector_type(4)));

// prepacked weight offsets in u16 units (each 128x128 matrix = 32768 u16 as hi/lo frags)
#define ENC_OFF 0
#define W1_OFF  32768
#define W2_OFF  65536
#define WG0_OFF 98304
#define WG1_OFF 131072
#define DEC_OFF 163840
#define WPK_TOT 196608

// ---- fp16 scaled two-term split: x ~= hi + lo*2^-12, |err| <= ~2^-23 |x| ----
__device__ __forceinline__ u16 f2h(float v) {
    _Float16 h = (_Float16)v;                       // v_cvt_f16_f32, RNE
    return __builtin_bit_cast(u16, h);
}
__device__ __forceinline__ float h2f(u16 u) {
    return (float)__builtin_bit_cast(_Float16, u);
}
__device__ __forceinline__ u16 split_hi(float v) { return f2h(v); }
__device__ __forceinline__ u16 split_lo(float v, u16 hi) {
    return f2h((v - h2f(hi)) * LOSCL);              // v-hi exact in fp32; *2^12 exact
}
__device__ __forceinline__ float gelu_exact(float x) {
    // exact erf GELU: approx GELU re-rolls the chaotic trajectory (rounds 2/3).
    return 0.5f * x * (1.0f + erff(x * 0.70710678118654752f));
}

// MFMA via BUILTIN: compiler models hazards/latency (round 6/7 NaN suspect was
// opaque inline-asm MFMA missing hazard nops in tight resident-register chains).
__device__ __forceinline__ void mfma16(f32x4& d, s16x8 a, s16x8 b) {
    d = __builtin_amdgcn_mfma_f32_16x16x32_f16(
            __builtin_bit_cast(h16x8, a), __builtin_bit_cast(h16x8, b), d, 0, 0, 0);
}
__device__ __forceinline__ s16x8 ldf(const u16* p) {
    return *reinterpret_cast<const s16x8*>(p);
}

// ---------------- weight prepack: fp32 -> fp16 hi / scaled-lo fragments ----------------
// frag layout: base + ((nt*4 + kc)*2 + term)*512 + lane*8 + i   (u16 units)
// element: B[k = kc*32 + (lane>>4)*8 + i][n = nt*16 + (lane&15)]
// sigma column-deinterleaved: WG0 = sig_w[:,0::2], WG1 = sig_w[:,1::2]
__global__ void prepack(const float* __restrict__ enc_w, const float* __restrict__ mu_w1,
                        const float* __restrict__ mu_w2, const float* __restrict__ sig_w,
                        const float* __restrict__ dec_w, u16* __restrict__ wpk)
{
    int u = blockIdx.x * 256 + threadIdx.x;
    if (u >= WPK_TOT) return;
    int mat  = u >> 15;
    int r    = u & 32767;
    int i    = r & 7;
    int lane = (r >> 3) & 63;
    int term = (r >> 9) & 1;
    int kc   = (r >> 10) & 3;
    int nt   = (r >> 12) & 7;
    int k = kc * 32 + (lane >> 4) * 8 + i;
    int n = nt * 16 + (lane & 15);
    float v;
    switch (mat) {
        case 0:  v = enc_w[k * 128 + n];         break;
        case 1:  v = mu_w1[k * 128 + n];         break;
        case 2:  v = mu_w2[k * 128 + n];         break;
        case 3:  v = sig_w[k * 256 + 2 * n];     break;
        case 4:  v = sig_w[k * 256 + 2 * n + 1]; break;
        default: v = dec_w[k * 128 + n];         break;
    }
    u16 hi = split_hi(v);
    wpk[u] = term ? split_lo(v, hi) : hi;
}

// ---------------- main fused SDE kernel ----------------
// 8 waves/block, each owns 16 cols. W1/W2/Wg0/Wg1 strips VGPR-resident per
// wave = 128 VGPRs. Zero d_ws reads in the step loop (r5 counters: in-loop
// weight reads -> 10.2 GB HBM fetch, 80% latency stall).
__global__ __launch_bounds__(NT, 1) void sde_mfma(
    const float* __restrict__ y, const float* __restrict__ noise,
    const float* __restrict__ enc_b, const float* __restrict__ mu_b1,
    const float* __restrict__ mu_b2, const float* __restrict__ sig_b,
    const float* __restrict__ dec_b, const u16* __restrict__ wpk,
    float* __restrict__ out, int Btot)
{
    __shared__ __align__(16) u16 zbh[8192];
    __shared__ __align__(16) u16 zbl[8192];
    __shared__ __align__(16) u16 hbh[8192];
    __shared__ __align__(16) u16 hbl[8192];
    __shared__ float nsb[2][128];

    const int tid  = threadIdx.x;
    const int lane = tid & 63, wid = tid >> 6;      // wid 0..7
    const int ln   = lane & 15, lg = lane >> 4;
    const size_t brow = (size_t)blockIdx.x * BR;

    const int n0 = wid * 16 + ln;                   // this thread's single col
    const float be0 = enc_b[n0];
    const float b10 = mu_b1[n0];
    const float b20 = mu_b2[n0];
    const float bg0 = sig_b[2 * n0];
    const float bg1 = sig_b[2 * n0 + 1];
    const float bd0 = dec_b[n0];

    // ---- resident weight strips: 4 matrices x (hi,lo) x kc4 = 32 s16x8 = 128 VGPRs ----
    s16x8 w1h[4], w1l[4], w2h[4], w2l[4];
    s16x8 g0h[4], g0l[4], g1h[4], g1l[4];
    #pragma unroll
    for (int kc = 0; kc < 4; kc++) {
        int fo = (((wid << 2) | kc) << 10) + (lane << 3);
        w1h[kc] = ldf(wpk + W1_OFF  + fo); w1l[kc] = ldf(wpk + W1_OFF  + fo + 512);
        w2h[kc] = ldf(wpk + W2_OFF  + fo); w2l[kc] = ldf(wpk + W2_OFF  + fo + 512);
        g0h[kc] = ldf(wpk + WG0_OFF + fo); g0l[kc] = ldf(wpk + WG0_OFF + fo + 512);
        g1h[kc] = ldf(wpk + WG1_OFF + fo); g1l[kc] = ldf(wpk + WG1_OFF + fo + 512);
    }

    float zr[4][4];   // z state: elem (m = 16*mt + 4*lg + r, n = n0)

    // ---- stage y into zb (fp16 hi/lo, swizzled) ----
    #pragma unroll
    for (int c = 0; c < 4; c++) {
        int q = c * NT + tid;                 // 0..2047
        int row = q >> 5, k4 = (q & 31) << 2;
        const float4 v = *reinterpret_cast<const float4*>(y + (brow + row) * 128 + k4);
        int idx = row * 128 + ((((k4 >> 3) ^ (row & 7))) << 3) + (k4 & 7);
        float vv[4] = {v.x, v.y, v.z, v.w};
        us4 hv, lv;
        #pragma unroll
        for (int e = 0; e < 4; e++) {
            u16 h = split_hi(vv[e]);
            u16 l = split_lo(vv[e], h);
            hv[e] = h; lv[e] = l;
        }
        *reinterpret_cast<us4*>(zbh + idx) = hv;
        *reinterpret_cast<us4*>(zbl + idx) = lv;
    }
    __syncthreads();

    // ---- encoder: z0 = gelu_exact(y @ enc_w + enc_b) ----
    {
        f32x4 a0[4], a1[4];
        #pragma unroll
        for (int mt = 0; mt < 4; mt++) {
            a0[mt] = f32x4{be0, be0, be0, be0};
            a1[mt] = f32x4{0, 0, 0, 0};
        }
        #pragma unroll
        for (int kc = 0; kc < 4; kc++) {
            s16x8 ah[4], al[4];
            #pragma unroll
            for (int mt = 0; mt < 4; mt++) {
                int row = mt * 16 + ln;
                int idx = row * 128 + ((((kc << 2) | lg) ^ (row & 7)) << 3);
                ah[mt] = ldf(zbh + idx);
                al[mt] = ldf(zbl + idx);
            }
            int fo = (((wid << 2) | kc) << 10) + (lane << 3);
            s16x8 bh = ldf(wpk + ENC_OFF + fo);
            s16x8 bl = ldf(wpk + ENC_OFF + fo + 512);
            #pragma unroll
            for (int mt = 0; mt < 4; mt++) {
                mfma16(a0[mt], ah[mt], bh);
                mfma16(a1[mt], al[mt], bh);
                mfma16(a1[mt], ah[mt], bl);
            }
        }
        #pragma unroll
        for (int mt = 0; mt < 4; mt++)
            #pragma unroll
            for (int r = 0; r < 4; r++)
                zr[mt][r] = gelu_exact(fmaf(a1[mt][r], LOINV, a0[mt][r]));
    }
    __syncthreads();   // all reads of y-tile done

    // write z0 into zb; stage noise for t=0
    #pragma unroll
    for (int mt = 0; mt < 4; mt++)
        #pragma unroll
        for (int r = 0; r < 4; r++) {
            int m = 16 * mt + 4 * lg + r;
            int idx = m * 128 + ((((n0 >> 3) ^ (m & 7))) << 3) + (n0 & 7);
            u16 h = split_hi(zr[mt][r]);
            zbh[idx] = h;
            zbl[idx] = split_lo(zr[mt][r], h);
        }
    if (tid < 128) nsb[0][tid] = noise[brow * 2 + tid];
    __syncthreads();

    // ---- 200 Euler-Maruyama steps, 2 barriers each, zero global loads except noise ----
    for (int t = 0; t < NSTEPS; t++) {
        {   // prefetch next step's noise into the other buffer
            int tn = (t + 1 < NSTEPS) ? (t + 1) : t;
            if (tid < 128) nsb[(t + 1) & 1][tid] = noise[((size_t)tn * Btot + brow) * 2 + tid];
        }
        // pass 1 — G1: h = gelu(z @ W1 + b1) -> hb (W1 resident)
        {
            f32x4 a0[4], a1[4];
            #pragma unroll
            for (int mt = 0; mt < 4; mt++) {
                a0[mt] = f32x4{b10, b10, b10, b10};
                a1[mt] = f32x4{0, 0, 0, 0};
            }
            #pragma unroll
            for (int kc = 0; kc < 4; kc++) {
                s16x8 ah[4], al[4];
                #pragma unroll
                for (int mt = 0; mt < 4; mt++) {
                    int row = mt * 16 + ln;
                    int idx = row * 128 + ((((kc << 2) | lg) ^ (row & 7)) << 3);
                    ah[mt] = ldf(zbh + idx);
                    al[mt] = ldf(zbl + idx);
                }
                #pragma unroll
                for (int mt = 0; mt < 4; mt++) {
                    mfma16(a0[mt], ah[mt], w1h[kc]);
                    mfma16(a1[mt], al[mt], w1h[kc]);
                    mfma16(a1[mt], ah[mt], w1l[kc]);
                }
            }
            #pragma unroll
            for (int mt = 0; mt < 4; mt++)
                #pragma unroll
                for (int r = 0; r < 4; r++) {
                    float hv = gelu_exact(fmaf(a1[mt][r], LOINV, a0[mt][r]));
                    int m = 16 * mt + 4 * lg + r;
                    int idx = m * 128 + ((((n0 >> 3) ^ (m & 7))) << 3) + (n0 & 7);
                    u16 h = split_hi(hv);
                    hbh[idx] = h;
                    hbl[idx] = split_lo(hv, h);
                }
        }
        // pass 2 — sigma: z += g0*dw0 + g1*dw1 (Wg0/Wg1 resident, one A-read)
        {
            f32x4 p0h_[4], p0l_[4], p1h_[4], p1l_[4];
            #pragma unroll
            for (int mt = 0; mt < 4; mt++) {
                p0h_[mt] = f32x4{bg0, bg0, bg0, bg0}; p0l_[mt] = f32x4{0, 0, 0, 0};
                p1h_[mt] = f32x4{bg1, bg1, bg1, bg1}; p1l_[mt] = f32x4{0, 0, 0, 0};
            }
            #pragma unroll
            for (int kc = 0; kc < 4; kc++) {
                s16x8 ah[4], al[4];
                #pragma unroll
                for (int mt = 0; mt < 4; mt++) {
                    int row = mt * 16 + ln;
                    int idx = row * 128 + ((((kc << 2) | lg) ^ (row & 7)) << 3);
                    ah[mt] = ldf(zbh + idx);
                    al[mt] = ldf(zbl + idx);
                }
                #pragma unroll
                for (int mt = 0; mt < 4; mt++) {
                    mfma16(p0h_[mt], ah[mt], g0h[kc]);
                    mfma16(p0l_[mt], al[mt], g0h[kc]);
                    mfma16(p0l_[mt], ah[mt], g0l[kc]);
                    mfma16(p1h_[mt], ah[mt], g1h[kc]);
                    mfma16(p1l_[mt], al[mt], g1h[kc]);
                    mfma16(p1l_[mt], ah[mt], g1l[kc]);
                }
            }
            const float* np = nsb[t & 1];
            #pragma unroll
            for (int mt = 0; mt < 4; mt++)
                #pragma unroll
                for (int r = 0; r < 4; r++) {
                    int m = 16 * mt + 4 * lg + r;
                    float dw0 = np[2 * m] * SQDT_F;
                    float dw1 = np[2 * m + 1] * SQDT_F;
                    float gv0 = fmaf(p0l_[mt][r], LOINV, p0h_[mt][r]);
                    float gv1 = fmaf(p1l_[mt][r], LOINV, p1h_[mt][r]);
                    zr[mt][r] = fmaf(gv0, dw0, fmaf(gv1, dw1, zr[mt][r]));
                }
        }
        __syncthreads();   // bar1: hb visible; all zb reads complete

        // pass 3 — G2: drift = h @ W2 + b2; z += drift*dt; rewrite zb (W2 resident)
        {
            f32x4 a0[4], a1[4];
            #pragma unroll
            for (int mt = 0; mt < 4; mt++) {
                a0[mt] = f32x4{b20, b20, b20, b20};
                a1[mt] = f32x4{0, 0, 0, 0};
            }
            #pragma unroll
            for (int kc = 0; kc < 4; kc++) {
                s16x8 ah[4], al[4];
                #pragma unroll
                for (int mt = 0; mt < 4; mt++) {
                    int row = mt * 16 + ln;
                    int idx = row * 128 + ((((kc << 2) | lg) ^ (row & 7)) << 3);
                    ah[mt] = ldf(hbh + idx);
                    al[mt] = ldf(hbl + idx);
                }
                #pragma unroll
                for (int mt = 0; mt < 4; mt++) {
                    mfma16(a0[mt], ah[mt], w2h[kc]);
                    mfma16(a1[mt], al[mt], w2h[kc]);
                    mfma16(a1[mt], ah[mt], w2l[kc]);
                }
            }
            #pragma unroll
            for (int mt = 0; mt < 4; mt++)
                #pragma unroll
                for (int r = 0; r < 4; r++) {
                    float v = fmaf(fmaf(a1[mt][r], LOINV, a0[mt][r]), DT_F, zr[mt][r]);
                    zr[mt][r] = v;
                    int m = 16 * mt + 4 * lg + r;
                    int idx = m * 128 + ((((n0 >> 3) ^ (m & 7))) << 3) + (n0 & 7);
                    u16 h = split_hi(v);
                    zbh[idx] = h;
                    zbl[idx] = split_lo(v, h);
                }
        }
        __syncthreads();   // bar2: new zb visible
    }

    // ---- decoder: out = z @ dec_w + dec_b ----
    {
        f32x4 a0[4], a1[4];
        #pragma unroll
        for (int mt = 0; mt < 4; mt++) {
            a0[mt] = f32x4{bd0, bd0, bd0, bd0};
            a1[mt] = f32x4{0, 0, 0, 0};
        }
        #pragma unroll
        for (int kc = 0; kc < 4; kc++) {
            s16x8 ah[4], al[4];
            #pragma unroll
            for (int mt = 0; mt < 4; mt++) {
                int row = mt * 16 + ln;
                int idx = row * 128 + ((((kc << 2) | lg) ^ (row & 7)) << 3);
                ah[mt] = ldf(zbh + idx);
                al[mt] = ldf(zbl + idx);
            }
            int fo = (((wid << 2) | kc) << 10) + (lane << 3);
            s16x8 bh = ldf(wpk + DEC_OFF + fo);
            s16x8 bl = ldf(wpk + DEC_OFF + fo + 512);
            #pragma unroll
            for (int mt = 0; mt < 4; mt++) {
                mfma16(a0[mt], ah[mt], bh);
                mfma16(a1[mt], al[mt], bh);
                mfma16(a1[mt], ah[mt], bl);
            }
        }
        #pragma unroll
        for (int mt = 0; mt < 4; mt++)
            #pragma unroll
            for (int r = 0; r < 4; r++) {
                int m = 16 * mt + 4 * lg + r;
                out[(brow + m) * 128 + n0] = fmaf(a1[mt][r], LOINV, a0[mt][r]);
            }
    }
}

extern "C" void kernel_launch(void* const* d_in, const int* in_sizes, int n_in,
                              void* d_out, int out_size, void* d_ws, size_t ws_size,
                              hipStream_t stream) {
    const float* y     = (const float*)d_in[0];
    const float* noise = (const float*)d_in[1];
    const float* enc_w = (const float*)d_in[2];
    const float* enc_b = (const float*)d_in[3];
    const float* mu_w1 = (const float*)d_in[4];
    const float* mu_b1 = (const float*)d_in[5];
    const float* mu_w2 = (const float*)d_in[6];
    const float* mu_b2 = (const float*)d_in[7];
    const float* sig_w = (const float*)d_in[8];
    const float* sig_b = (const float*)d_in[9];
    const float* dec_w = (const float*)d_in[10];
    const float* dec_b = (const float*)d_in[11];
    float* out = (float*)d_out;
    u16* wpk = (u16*)d_ws;

    const int Btot = in_sizes[0] / 128;     // 32768
    prepack<<<(WPK_TOT + 255) / 256, 256, 0, stream>>>(enc_w, mu_w1, mu_w2, sig_w, dec_w, wpk);
    sde_mfma<<<Btot / BR, NT, 0, stream>>>(y, noise, enc_b, mu_b1, mu_b2, sig_b, dec_b,
                                           wpk, out, Btot);
}